// Round 4
// baseline (22651.089 us; speedup 1.0000x reference)
//
#include <hip/hip_runtime.h>
#include <math.h>

// Problem constants
#define BB     32      // batch
#define KBM    5       // beam width
#define NR     160     // BB*KBM rows (beam-major)
#define HD     512     // hidden
#define TT     256     // encoder time steps
#define VV     5000    // vocab
#define MAXLEN 64
#define EOSID  2
#define NEGV   (-1e9f)
#define SCALEF 0.04419417382415922f  // 1/sqrt(512)
#define NBLK   256

// ---- system-scope coherent (cache-bypass) access for MUTABLE buffers ----
// All cross-block mutable data uses these exclusively: no L1/L2 copies ever
// exist, so no fences / cache invalidations are needed anywhere.
__device__ __forceinline__ float ld_sysf(const float* p) {
  return __hip_atomic_load(p, __ATOMIC_RELAXED, __HIP_MEMORY_SCOPE_SYSTEM);
}
__device__ __forceinline__ void st_sysf(float* p, float v) {
  __hip_atomic_store(p, v, __ATOMIC_RELAXED, __HIP_MEMORY_SCOPE_SYSTEM);
}
__device__ __forceinline__ int ld_sysi(const int* p) {
  return __hip_atomic_load(p, __ATOMIC_RELAXED, __HIP_MEMORY_SCOPE_SYSTEM);
}
__device__ __forceinline__ void st_sysi(int* p, int v) {
  __hip_atomic_store(p, v, __ATOMIC_RELAXED, __HIP_MEMORY_SCOPE_SYSTEM);
}

// comparator matching jax.lax.top_k stability: value desc, index asc on ties
__device__ __forceinline__ bool viBetter(float av, int ai, float bv, int bi) {
  return (av > bv) || (av == bv && ai < bi);
}

__device__ __forceinline__ void top5_insert(float tv[5], int ti[5], float x, int v) {
  if (!viBetter(x, v, tv[4], ti[4])) return;
  tv[4] = x; ti[4] = v;
#pragma unroll
  for (int q = 4; q > 0; q--) {
    if (viBetter(tv[q], ti[q], tv[q - 1], ti[q - 1])) {
      float tf = tv[q - 1]; int tx2 = ti[q - 1];
      tv[q - 1] = tv[q]; ti[q - 1] = ti[q];
      tv[q] = tf; ti[q] = tx2;
    } else break;
  }
}

__global__ void k_zero(unsigned int* bar) { *bar = 0u; }  // kernel-end release flushes

__launch_bounds__(256, 1)
__global__ void k_persist(const int* __restrict__ input_var, const float* __restrict__ enc,
                          const float* __restrict__ emb, const float* __restrict__ w_ih,
                          const float* __restrict__ w_hh, const float* __restrict__ w_out,
                          float* __restrict__ out,
                          float* h, float* A_cat, float* logits, int* tokens,
                          float* cum, int* finished, int* lengths, int* last_tok,
                          unsigned int* bar) {
  const int bid = blockIdx.x;
  const int tid = threadIdx.x;
  unsigned int btarget = 0;

  // ---- shared memory (~100KB -> 1 block/CU; 256 blocks co-resident) ----
  __shared__ float sh_xs[32][36];         // gru
  __shared__ float sh_hs[32][36];
  __shared__ float sh_ws[6][32][32];
  __shared__ int   sh_toks[32];
  __shared__ float sh_h5[KBM][HD];        // attn: 5 beam hidden vectors
  __shared__ float sh_sc5[KBM][TT];       // attn: scores / weights
  __shared__ float sh_tmp5[KBM][TT];      // attn: reduction scratch
  __shared__ float sh_red[256];           // generic reductions
  __shared__ float sh_red2[256];
  __shared__ float sh_as[32][33];         // gemm
  __shared__ float sh_bs[32][132];
  __shared__ float sh_sv0[256 * 5]; __shared__ int sh_si0[256 * 5];
  __shared__ float sh_sv1[256 * 5]; __shared__ int sh_si1[256 * 5];
  __shared__ float sh_candV[KBM * KBM]; __shared__ int sh_candI[KBM * KBM];
  __shared__ float sh_oc[KBM]; __shared__ int sh_ofin[KBM]; __shared__ int sh_olen[KBM];
  __shared__ int   sh_ttmp[KBM * MAXLEN];
  __shared__ int   sh_selI[KBM]; __shared__ float sh_selV[KBM];

  // ---- fence-free grid barrier: all shared data is cache-bypass coherent ----
  auto gbar = [&]() {
    __syncthreads();           // each wave drains its vmcnt before s_barrier
    btarget += NBLK;
    if (tid == 0) {
      __hip_atomic_fetch_add(bar, 1u, __ATOMIC_RELAXED, __HIP_MEMORY_SCOPE_SYSTEM);
      while (__hip_atomic_load(bar, __ATOMIC_RELAXED, __HIP_MEMORY_SCOPE_SYSTEM) < btarget) {
        __builtin_amdgcn_s_sleep(2);
      }
    }
    __syncthreads();
  };

  // ---- per-row online-LSE + top5 (used by topk phases); results in
  //      sh_sv0[0..4]/sh_si0[0..4], returns lse. Uniform control flow. ----
  auto proc_row = [&](const float* lrow) -> float {
    float tv[5]; int ti[5];
#pragma unroll
    for (int q = 0; q < 5; q++) { tv[q] = -INFINITY; ti[q] = 0x7fffffff; }
    float m = -INFINITY, s = 0.f;
    for (int v = tid; v < VV; v += 256) {
      float x = ld_sysf(&lrow[v]);
      float mn = fmaxf(m, x);
      s = s * expf(m - mn) + expf(x - mn);
      m = mn;
      top5_insert(tv, ti, x, v);
    }
    sh_red[tid] = m; sh_red2[tid] = s;
    __syncthreads();
    for (int off = 128; off > 0; off >>= 1) {
      if (tid < off) {
        float m1 = sh_red[tid], m2 = sh_red[tid + off];
        float s1 = sh_red2[tid], s2 = sh_red2[tid + off];
        float mm = fmaxf(m1, m2);
        sh_red[tid] = mm;
        sh_red2[tid] = s1 * expf(m1 - mm) + s2 * expf(m2 - mm);
      }
      __syncthreads();
    }
    float lse = sh_red[0] + logf(sh_red2[0]);
    __syncthreads();
#pragma unroll
    for (int q = 0; q < 5; q++) { sh_sv0[tid * 5 + q] = tv[q]; sh_si0[tid * 5 + q] = ti[q]; }
    __syncthreads();
    int cur = 0;
    for (int off = 128; off > 0; off >>= 1) {
      float* svc = cur ? sh_sv1 : sh_sv0; int* sic = cur ? sh_si1 : sh_si0;
      float* svn = cur ? sh_sv0 : sh_sv1; int* sinn = cur ? sh_si0 : sh_si1;
      if (tid < off) {
        int ia = 0, ib = 0;
        int baseA = tid * 5, baseB = (tid + off) * 5;
#pragma unroll
        for (int q = 0; q < 5; q++) {
          float va = svc[baseA + ia]; int xa = sic[baseA + ia];
          float vb = svc[baseB + ib]; int xb = sic[baseB + ib];
          bool ta = viBetter(va, xa, vb, xb);
          svn[baseA + q] = ta ? va : vb;
          sinn[baseA + q] = ta ? xa : xb;
          ia += ta ? 1 : 0; ib += ta ? 0 : 1;
        }
      }
      cur ^= 1;
      __syncthreads();
    }
    return lse;   // 8 levels -> result back in sv0/si0
  };

  // ---- init: h=0, tokens=0, last_tok=SOS (all via bypass stores) ----
  {
    int gidx = bid * 256 + tid;
    const int gstride = NBLK * 256;
    for (int t = gidx; t < NR * HD; t += gstride) st_sysf(&h[t], 0.f);
    for (int t = gidx; t < BB * KBM * MAXLEN; t += gstride) st_sysi(&tokens[t], 0);
    for (int t = gidx; t < NR; t += gstride) st_sysi(&last_tok[t], input_var[t / KBM]);
  }
  gbar();

  for (int di = 0; di < MAXLEN; di++) {
    // ================= GRU (80 blocks: 16 col-tiles x 5 row-tiles) =========
    if (bid < 80) {
      const int bx = bid & 15, by = bid >> 4;
      const int tx = tid & 31, ty = tid >> 5;
      const int i0 = bx * 32;
      const int n0 = by * 32;
      if (tid < 32) sh_toks[tid] = ld_sysi(&last_tok[n0 + tid]);
      float acc[6][4];
#pragma unroll
      for (int g = 0; g < 6; g++)
#pragma unroll
        for (int rr = 0; rr < 4; rr++) acc[g][rr] = 0.f;

      for (int k0 = 0; k0 < HD; k0 += 32) {
        __syncthreads();
        {
          int r = tid >> 3, c4 = (tid & 7) * 4;
          // emb: immutable -> cached vector load
          *reinterpret_cast<float4*>(&sh_xs[r][c4]) =
              *reinterpret_cast<const float4*>(&emb[(size_t)sh_toks[r] * HD + k0 + c4]);
          // h: mutable -> bypass scalar loads
          const float* hp = &h[(size_t)(n0 + r) * HD + k0 + c4];
          float4 hv4;
          hv4.x = ld_sysf(hp + 0); hv4.y = ld_sysf(hp + 1);
          hv4.z = ld_sysf(hp + 2); hv4.w = ld_sysf(hp + 3);
          *reinterpret_cast<float4*>(&sh_hs[r][c4]) = hv4;
        }
#pragma unroll
        for (int g = 0; g < 6; g++) {
          int kk = tid >> 3, c4 = (tid & 7) * 4;
          const float* W = (g < 3) ? w_ih : w_hh;
          int gc = (g < 3) ? g : (g - 3);
          *reinterpret_cast<float4*>(&sh_ws[g][kk][c4]) =
              *reinterpret_cast<const float4*>(&W[(size_t)(k0 + kk) * 1536 + gc * HD + i0 + c4]);
        }
        __syncthreads();
#pragma unroll
        for (int kk = 0; kk < 32; kk++) {
          float w0 = sh_ws[0][kk][tx], w1 = sh_ws[1][kk][tx], w2 = sh_ws[2][kk][tx];
          float w3 = sh_ws[3][kk][tx], w4 = sh_ws[4][kk][tx], w5 = sh_ws[5][kk][tx];
#pragma unroll
          for (int rr = 0; rr < 4; rr++) {
            float xv = sh_xs[ty * 4 + rr][kk];
            float hv = sh_hs[ty * 4 + rr][kk];
            acc[0][rr] += xv * w0;
            acc[1][rr] += xv * w1;
            acc[2][rr] += xv * w2;
            acc[3][rr] += hv * w3;
            acc[4][rr] += hv * w4;
            acc[5][rr] += hv * w5;
          }
        }
      }
#pragma unroll
      for (int rr = 0; rr < 4; rr++) {
        int n = n0 + ty * 4 + rr;
        int i = i0 + tx;
        float hv = ld_sysf(&h[(size_t)n * HD + i]);
        float z = 1.f / (1.f + expf(-(acc[0][rr] + acc[3][rr])));
        float r = 1.f / (1.f + expf(-(acc[1][rr] + acc[4][rr])));
        float nn = tanhf(acc[2][rr] + r * acc[5][rr]);
        st_sysf(&A_cat[(size_t)n * 1024 + i], (1.f - z) * nn + z * hv);
      }
    }
    gbar();

    // ============ attention (32 blocks: one per BATCH, 5 beams share enc) ==
    if (bid < BB) {
      const int b = bid;
      for (int idx = tid; idx < KBM * HD; idx += 256) {
        int j = idx >> 9, kc = idx & 511;
        sh_h5[j][kc] = ld_sysf(&A_cat[(size_t)(b * KBM + j) * 1024 + kc]);
      }
      __syncthreads();
      // pass 1: scores for timestep t=tid, all 5 beams (enc cached, L2-hot)
      float acc[KBM];
#pragma unroll
      for (int j = 0; j < KBM; j++) acc[j] = 0.f;
      const float* ep = enc + ((size_t)b * TT + tid) * HD;
      for (int k = 0; k < HD; k += 4) {
        float4 e = *reinterpret_cast<const float4*>(ep + k);
#pragma unroll
        for (int j = 0; j < KBM; j++) {
          acc[j] += sh_h5[j][k] * e.x + sh_h5[j][k + 1] * e.y +
                    sh_h5[j][k + 2] * e.z + sh_h5[j][k + 3] * e.w;
        }
      }
#pragma unroll
      for (int j = 0; j < KBM; j++) {
        float s = acc[j] * SCALEF;
        sh_sc5[j][tid] = s;
        sh_tmp5[j][tid] = s;
      }
      __syncthreads();
      for (int off = 128; off > 0; off >>= 1) {
        if (tid < off) {
#pragma unroll
          for (int j = 0; j < KBM; j++)
            sh_tmp5[j][tid] = fmaxf(sh_tmp5[j][tid], sh_tmp5[j][tid + off]);
        }
        __syncthreads();
      }
      float mj[KBM];
#pragma unroll
      for (int j = 0; j < KBM; j++) mj[j] = sh_tmp5[j][0];
      __syncthreads();
      float ej[KBM];
#pragma unroll
      for (int j = 0; j < KBM; j++) {
        ej[j] = expf(sh_sc5[j][tid] - mj[j]);
        sh_tmp5[j][tid] = ej[j];
      }
      __syncthreads();
      for (int off = 128; off > 0; off >>= 1) {
        if (tid < off) {
#pragma unroll
          for (int j = 0; j < KBM; j++)
            sh_tmp5[j][tid] += sh_tmp5[j][tid + off];
        }
        __syncthreads();
      }
#pragma unroll
      for (int j = 0; j < KBM; j++) sh_sc5[j][tid] = ej[j] / sh_tmp5[j][0];
      __syncthreads();
      // pass 2: context cols (2*tid, 2*tid+1), all 5 beams (enc L2-hit)
      float cx[KBM], cy[KBM];
#pragma unroll
      for (int j = 0; j < KBM; j++) { cx[j] = 0.f; cy[j] = 0.f; }
      const float* eb = enc + (size_t)b * TT * HD + 2 * tid;
      for (int t = 0; t < TT; t++) {
        float2 e2 = *reinterpret_cast<const float2*>(eb + (size_t)t * HD);
#pragma unroll
        for (int j = 0; j < KBM; j++) {
          float w = sh_sc5[j][t];
          cx[j] += w * e2.x; cy[j] += w * e2.y;
        }
      }
#pragma unroll
      for (int j = 0; j < KBM; j++) {
        float* dst = &A_cat[(size_t)(b * KBM + j) * 1024 + HD + 2 * tid];
        st_sysf(dst + 0, cx[j]);
        st_sysf(dst + 1, cy[j]);
      }
    }
    gbar();

    // ================= output GEMM (200 blocks: 40 col x 5 row tiles) ======
    if (bid < 200) {
      const int tx = tid & 31, ty = tid >> 5;
      const int c0 = (bid % 40) * 128;
      const int n0 = (bid / 40) * 32;
      float acc[4][4];
#pragma unroll
      for (int rr = 0; rr < 4; rr++)
#pragma unroll
        for (int cc = 0; cc < 4; cc++) acc[rr][cc] = 0.f;

      for (int k0 = 0; k0 < 1024; k0 += 32) {
        __syncthreads();
#pragma unroll
        for (int p = 0; p < 4; p++) {
          int idx = tid + p * 256;
          int r = idx >> 5, kk = idx & 31;
          sh_as[r][kk] = ld_sysf(&A_cat[(size_t)(n0 + r) * 1024 + k0 + kk]);
        }
#pragma unroll
        for (int p = 0; p < 4; p++) {
          int idx = tid + p * 256;      // 32 kk x 32 vec4 (w_out cached, L2-hot)
          int kk = idx >> 5;
          int c4 = (idx & 31) * 4;
          int col = c0 + c4;
          float4 v;
          if (col + 3 < VV) {
            v = *reinterpret_cast<const float4*>(&w_out[(size_t)(k0 + kk) * VV + col]);
          } else {
            v.x = v.y = v.z = v.w = 0.f;
          }
          *reinterpret_cast<float4*>(&sh_bs[kk][c4]) = v;
        }
        __syncthreads();
#pragma unroll
        for (int kk = 0; kk < 32; kk++) {
          float bv[4];
#pragma unroll
          for (int cc = 0; cc < 4; cc++) bv[cc] = sh_bs[kk][tx * 4 + cc];
#pragma unroll
          for (int rr = 0; rr < 4; rr++) {
            float av = sh_as[ty * 4 + rr][kk];
#pragma unroll
            for (int cc = 0; cc < 4; cc++) acc[rr][cc] += av * bv[cc];
          }
        }
      }
#pragma unroll
      for (int rr = 0; rr < 4; rr++) {
        int n = n0 + ty * 4 + rr;
#pragma unroll
        for (int cc = 0; cc < 4; cc++) {
          int c = c0 + tx * 4 + cc;
          if (c < VV) st_sysf(&logits[(size_t)n * VV + c], acc[rr][cc]);
        }
      }
    }
    gbar();

    // ====== top-k (32 blocks: per batch; online LSE; merge; state update) ==
    if (bid < BB) {
      const int b = bid;
      if (di == 0) {
        // first step: top-5 of replica j=0 row seeds the beams
        float lse = proc_row(logits + (size_t)(b * KBM) * VV);
        if (tid < KBM) {
          int tk = sh_si0[tid];
          st_sysf(&cum[b * KBM + tid], sh_sv0[tid] - lse);
          st_sysi(&finished[b * KBM + tid], (tk == EOSID) ? 1 : 0);
          st_sysi(&lengths[b * KBM + tid], 1);
          st_sysi(&last_tok[b * KBM + tid], tk);
          st_sysi(&tokens[b * KBM * MAXLEN + tid * MAXLEN], tk);
        }
        for (int t = tid; t < KBM * HD; t += 256) {
          int p = t >> 9, e2 = t & 511;
          st_sysf(&h[(size_t)(b * KBM + p) * HD + e2],
                  ld_sysf(&A_cat[(size_t)(b * KBM + p) * 1024 + e2]));
        }
      } else {
        if (tid < KBM) {
          sh_oc[tid] = ld_sysf(&cum[b * KBM + tid]);
          sh_ofin[tid] = ld_sysi(&finished[b * KBM + tid]);
          sh_olen[tid] = ld_sysi(&lengths[b * KBM + tid]);
        }
        for (int t = tid; t < KBM * MAXLEN; t += 256)
          sh_ttmp[t] = ld_sysi(&tokens[b * KBM * MAXLEN + t]);
        __syncthreads();

        for (int j = 0; j < KBM; j++) {
          if (sh_ofin[j]) {      // uniform branch
            if (tid == 0) {
              float cj = sh_oc[j];
              sh_candV[j * KBM + 0] = cj;             // PAD at zero log-prob
              sh_candI[j * KBM + 0] = j * VV + 0;
#pragma unroll
              for (int q = 1; q < KBM; q++) {
                sh_candV[j * KBM + q] = cj + NEGV;
                sh_candI[j * KBM + q] = j * VV + q;
              }
            }
            __syncthreads();
          } else {
            float lse = proc_row(logits + (size_t)(b * KBM + j) * VV);
            if (tid == 0) {
              float cj = sh_oc[j];
#pragma unroll
              for (int q = 0; q < 5; q++) {
                sh_candV[j * KBM + q] = cj + (sh_sv0[q] - lse);
                sh_candI[j * KBM + q] = j * VV + sh_si0[q];
              }
            }
            __syncthreads();
          }
        }

        if (tid == 0) {
          float fv[5]; int fi[5];
#pragma unroll
          for (int q = 0; q < 5; q++) { fv[q] = -INFINITY; fi[q] = 0x7fffffff; }
          for (int t = 0; t < KBM * KBM; t++)
            top5_insert(fv, fi, sh_candV[t], sh_candI[t]);
#pragma unroll
          for (int q = 0; q < 5; q++) { sh_selV[q] = fv[q]; sh_selI[q] = fi[q]; }
        }
        __syncthreads();
        if (tid < KBM) {
          int p = tid, idx = sh_selI[p];
          int bm = idx / VV, tk = idx - bm * VV;
          st_sysf(&cum[b * KBM + p], sh_selV[p]);
          int pf = sh_ofin[bm];
          st_sysi(&lengths[b * KBM + p], sh_olen[bm] + (pf ? 0 : 1));
          st_sysi(&finished[b * KBM + p], (pf || tk == EOSID) ? 1 : 0);
          st_sysi(&last_tok[b * KBM + p], tk);
        }
        for (int t = tid; t < KBM * MAXLEN; t += 256) {
          int p = t >> 6, pos = t & 63;
          int idx = sh_selI[p]; int bm = idx / VV; int tk = idx - bm * VV;
          st_sysi(&tokens[b * KBM * MAXLEN + t],
                  (pos == di) ? tk : sh_ttmp[bm * MAXLEN + pos]);
        }
        for (int t = tid; t < KBM * HD; t += 256) {
          int p = t >> 9, e2 = t & 511;
          int bm = sh_selI[p] / VV;
          st_sysf(&h[(size_t)(b * KBM + p) * HD + e2],
                  ld_sysf(&A_cat[(size_t)(b * KBM + bm) * 1024 + e2]));
        }
      }
    }
    gbar();
  }

  // ================= final: length penalty, best beam, outputs ============
  if (bid < BB) {
    const int b = bid;
    if (tid < KBM) {
      float c = ld_sysf(&cum[b * KBM + tid]);
      float pen = powf((5.0f + (float)ld_sysi(&lengths[b * KBM + tid])) / 6.0f, 1.2f);
      sh_red[tid] = ld_sysi(&finished[b * KBM + tid]) ? (c / pen) : c;
      sh_red2[tid] = c;
    }
    __syncthreads();
    if (tid == 0) {
      int best = 0; float bv = sh_red[0];
#pragma unroll
      for (int jj = 1; jj < KBM; jj++) {
        if (sh_red[jj] > bv) { bv = sh_red[jj]; best = jj; }
      }
      sh_selI[0] = best;
    }
    __syncthreads();
    if (tid < MAXLEN)
      out[b * MAXLEN + tid] =
          (float)ld_sysi(&tokens[b * KBM * MAXLEN + sh_selI[0] * MAXLEN + tid]);
    if (tid < KBM) out[BB * MAXLEN + b * KBM + tid] = sh_red2[tid];
  }
}

extern "C" void kernel_launch(void* const* d_in, const int* in_sizes, int n_in,
                              void* d_out, int out_size, void* d_ws, size_t ws_size,
                              hipStream_t stream) {
  (void)in_sizes; (void)n_in; (void)out_size; (void)ws_size;
  const int*   input_var = (const int*)d_in[0];
  const float* enc       = (const float*)d_in[1];
  const float* emb       = (const float*)d_in[2];
  const float* w_ih      = (const float*)d_in[3];
  const float* w_hh      = (const float*)d_in[4];
  const float* w_out     = (const float*)d_in[5];
  float* out = (float*)d_out;

  float* h      = (float*)d_ws;
  float* A_cat  = h + (size_t)NR * HD;
  float* logits = A_cat + (size_t)NR * 1024;
  int*   tokens = (int*)(logits + (size_t)NR * VV);
  float* cum    = (float*)(tokens + (size_t)BB * KBM * MAXLEN);
  int*   finished = (int*)(cum + NR);
  int*   lengths  = finished + NR;
  int*   last_tok = lengths + NR;
  unsigned int* bar = (unsigned int*)(last_tok + NR);

  k_zero<<<1, 1, 0, stream>>>(bar);
  k_persist<<<NBLK, 256, 0, stream>>>(input_var, enc, emb, w_ih, w_hh, w_out, out,
                                      h, A_cat, logits, tokens, cum, finished,
                                      lengths, last_tok, bar);
}

// Round 5
// 9874.342 us; speedup vs baseline: 2.2939x; 2.2939x over previous
//
#include <hip/hip_runtime.h>
#include <math.h>

// Problem constants
#define BB     32      // batch
#define KBM    5       // beam width
#define NR     160     // BB*KBM rows (beam-major)
#define HD     512     // hidden
#define TT     256     // encoder time steps
#define VV     5000    // vocab
#define MAXLEN 64
#define EOSID  2
#define NEGV   (-1e9f)
#define NEGBIG (-3.0e38f)
#define SCALEF 0.04419417382415922f  // 1/sqrt(512)
#define NBLK   256
#define NTHR   512

typedef float v4f __attribute__((ext_vector_type(4)));

// ---- coherent (L2-bypass) scalar ops for small mutable data [R4-proven] ----
__device__ __forceinline__ float ld_sysf(const float* p) {
  return __hip_atomic_load(p, __ATOMIC_RELAXED, __HIP_MEMORY_SCOPE_SYSTEM);
}
__device__ __forceinline__ void st_sysf(float* p, float v) {
  __hip_atomic_store(p, v, __ATOMIC_RELAXED, __HIP_MEMORY_SCOPE_SYSTEM);
}
__device__ __forceinline__ int ld_sysi(const int* p) {
  return __hip_atomic_load(p, __ATOMIC_RELAXED, __HIP_MEMORY_SCOPE_SYSTEM);
}
__device__ __forceinline__ void st_sysi(int* p, int v) {
  __hip_atomic_store(p, v, __ATOMIC_RELAXED, __HIP_MEMORY_SCOPE_SYSTEM);
}
// ---- coherent (L2-bypass) VECTOR ops for bulk mutable data ----
__device__ __forceinline__ v4f ld4_sys(const float* p) {
  v4f v;
  asm volatile("global_load_dwordx4 %0, %1, off sc0 sc1\n\ts_waitcnt vmcnt(0)"
               : "=v"(v) : "v"(p) : "memory");
  return v;
}
__device__ __forceinline__ void st4_sys(float* p, v4f v) {
  asm volatile("global_store_dwordx4 %0, %1, off sc0 sc1" :: "v"(p), "v"(v) : "memory");
}

// comparator matching jax.lax.top_k stability: value desc, index asc on ties
__device__ __forceinline__ bool viBetter(float av, int ai, float bv, int bi) {
  return (av > bv) || (av == bv && ai < bi);
}

__device__ __forceinline__ void top5_insert(float tv[5], int ti[5], float x, int v) {
  if (!viBetter(x, v, tv[4], ti[4])) return;
  tv[4] = x; ti[4] = v;
#pragma unroll
  for (int q = 4; q > 0; q--) {
    if (viBetter(tv[q], ti[q], tv[q - 1], ti[q - 1])) {
      float tf = tv[q - 1]; int tx2 = ti[q - 1];
      tv[q - 1] = tv[q]; ti[q - 1] = ti[q];
      tv[q] = tf; ti[q] = tx2;
    } else break;
  }
}

template<int LEVELS>
__device__ __forceinline__ void bfly_argmax(float& v, int& i) {
#pragma unroll
  for (int d = 1; d < (1 << LEVELS); d <<= 1) {
    float ov = __shfl_xor(v, d);
    int oi = __shfl_xor(i, d);
    if (viBetter(ov, oi, v, i)) { v = ov; i = oi; }
  }
}

__global__ void k_zero(unsigned int* bar) {
  if (threadIdx.x < 320)
    __hip_atomic_store(&bar[threadIdx.x], 0u, __ATOMIC_RELAXED, __HIP_MEMORY_SCOPE_SYSTEM);
}

__launch_bounds__(NTHR, 1)
__global__ void k_persist(const int* __restrict__ input_var, const float* __restrict__ enc,
                          const float* __restrict__ emb, const float* __restrict__ w_ih,
                          const float* __restrict__ w_hh, const float* __restrict__ w_out,
                          float* __restrict__ out,
                          float* h, float* A_cat,
                          float* sumM, float* sumS, float* sumV, int* sumI,
                          int* last_tok, unsigned int* bar) {
  const int bid = blockIdx.x;
  const int tid = threadIdx.x;
  unsigned int ep = 0;

  // ---------------- shared memory (~113KB -> 1 block/CU) ----------------
  __shared__ float sh_xs[32][40];
  __shared__ float sh_hs[32][40];
  __shared__ float sh_ws[6][32][32];
  __shared__ int   sh_toks[32];
  __shared__ float sh_h5[KBM][HD];
  __shared__ float sh_part[2][KBM][TT];
  __shared__ float sh_sc5[KBM][TT];
  __shared__ float sh_tmp5[KBM][TT];
  __shared__ float sh_as[32][72];
  __shared__ float sh_bs[64][136];
  __shared__ float sh_candV[KBM * KBM]; __shared__ int sh_candI[KBM * KBM];
  __shared__ int   sh_tokens[KBM][MAXLEN];   // persistent per-batch state (bid<32)
  __shared__ float sh_cum[KBM];
  __shared__ int   sh_fin[KBM]; __shared__ int sh_len[KBM];
  __shared__ float sh_oc[KBM];  __shared__ int sh_ofin[KBM]; __shared__ int sh_olen[KBM];
  __shared__ int   sh_ttmp[KBM * MAXLEN];
  __shared__ int   sh_selI[KBM]; __shared__ float sh_selV[KBM];

  // ---- fence-free tree barrier: 8 spread counters + epoch flag ----
  auto gbar = [&]() {
    asm volatile("s_waitcnt vmcnt(0)" ::: "memory");   // drain asm bypass stores
    __syncthreads();
    ep += 1;
    if (tid == 0) {
      __hip_atomic_fetch_add(&bar[(bid & 7) * 32], 1u, __ATOMIC_RELAXED,
                             __HIP_MEMORY_SCOPE_SYSTEM);
      if (bid == 0) {
        for (int c = 0; c < 8; c++) {
          while (__hip_atomic_load(&bar[c * 32], __ATOMIC_RELAXED,
                                   __HIP_MEMORY_SCOPE_SYSTEM) < ep * 32u) {
            __builtin_amdgcn_s_sleep(1);
          }
        }
        __hip_atomic_store(&bar[288], ep, __ATOMIC_RELAXED, __HIP_MEMORY_SCOPE_SYSTEM);
      } else {
        while (__hip_atomic_load(&bar[288], __ATOMIC_RELAXED,
                                 __HIP_MEMORY_SCOPE_SYSTEM) < ep) {
          __builtin_amdgcn_s_sleep(2);
        }
      }
    }
    __syncthreads();
  };

  // ---------------- init ----------------
  if (bid < BB) {
    if (tid < KBM) { sh_cum[tid] = 0.f; sh_fin[tid] = 0; sh_len[tid] = 0; }
    for (int t = tid; t < KBM * MAXLEN; t += NTHR) sh_tokens[t >> 6][t & 63] = 0;
  }
  {
    int gidx = bid * NTHR + tid;
    v4f z4; z4[0] = z4[1] = z4[2] = z4[3] = 0.f;
    for (int i = gidx; i < NR * HD / 4; i += NBLK * NTHR) st4_sys(&h[i * 4], z4);
    for (int t = gidx; t < NR; t += NBLK * NTHR) st_sysi(&last_tok[t], input_var[t / KBM]);
  }
  gbar();

  for (int di = 0; di < MAXLEN; di++) {
    // ============ GRU (80 blocks: 16 col-tiles x 5 row-tiles, 32x32) ======
    if (bid < 80) {
      const int bx = bid & 15, by = bid >> 4;
      const int i0 = bx * 32, n0 = by * 32;
      const int tx = tid & 31, ty = tid >> 5;    // ty 0..15, 2 rows each
      if (tid < 32) sh_toks[tid] = ld_sysi(&last_tok[n0 + tid]);
      float acc[6][2];
#pragma unroll
      for (int g = 0; g < 6; g++) { acc[g][0] = 0.f; acc[g][1] = 0.f; }

      for (int k0 = 0; k0 < HD; k0 += 32) {
        __syncthreads();
#pragma unroll
        for (int p = 0; p < 4; p++) {
          int idx = tid + p * NTHR;
          if (idx < 256) {
            int r = idx >> 3, c4 = (idx & 7) * 4;
            *(v4f*)&sh_xs[r][c4] =
                *(const v4f*)&emb[(size_t)sh_toks[r] * HD + k0 + c4];
          } else if (idx < 512) {
            int r = (idx - 256) >> 3, c4 = ((idx - 256) & 7) * 4;
            *(v4f*)&sh_hs[r][c4] = ld4_sys(&h[(size_t)(n0 + r) * HD + k0 + c4]);
          } else {
            int widx = idx - 512;                 // 0..1535
            int g = widx >> 8, rem = widx & 255;
            int kk = rem >> 3, c4 = (rem & 7) * 4;
            const float* W = (g < 3) ? w_ih : w_hh;
            int gc = (g < 3) ? g : g - 3;
            *(v4f*)&sh_ws[g][kk][c4] =
                *(const v4f*)&W[(size_t)(k0 + kk) * 1536 + gc * HD + i0 + c4];
          }
        }
        __syncthreads();
#pragma unroll 8
        for (int k = 0; k < 32; k++) {
          float w0 = sh_ws[0][k][tx], w1 = sh_ws[1][k][tx], w2 = sh_ws[2][k][tx];
          float w3 = sh_ws[3][k][tx], w4 = sh_ws[4][k][tx], w5 = sh_ws[5][k][tx];
#pragma unroll
          for (int rr = 0; rr < 2; rr++) {
            float xv = sh_xs[ty * 2 + rr][k];
            float hv = sh_hs[ty * 2 + rr][k];
            acc[0][rr] += xv * w0; acc[1][rr] += xv * w1; acc[2][rr] += xv * w2;
            acc[3][rr] += hv * w3; acc[4][rr] += hv * w4; acc[5][rr] += hv * w5;
          }
        }
      }
#pragma unroll
      for (int rr = 0; rr < 2; rr++) {
        int n = n0 + ty * 2 + rr, i = i0 + tx;
        float hv = ld_sysf(&h[(size_t)n * HD + i]);
        float z = 1.f / (1.f + expf(-(acc[0][rr] + acc[3][rr])));
        float r = 1.f / (1.f + expf(-(acc[1][rr] + acc[4][rr])));
        float nn = tanhf(acc[2][rr] + r * acc[5][rr]);
        st_sysf(&A_cat[(size_t)n * 1024 + i], (1.f - z) * nn + z * hv);
      }
    }
    gbar();

    // ============ attention (32 blocks: one per batch) ====================
    if (bid < BB) {
      const int b = bid;
      for (int idx = tid; idx < 640; idx += NTHR) {
        int j = idx >> 7, kc = (idx & 127) * 4;
        *(v4f*)&sh_h5[j][kc] = ld4_sys(&A_cat[(size_t)(b * KBM + j) * 1024 + kc]);
      }
      __syncthreads();
      {
        const int t = tid & 255, half = tid >> 8;
        const int kb = half * 256;
        float a[KBM];
#pragma unroll
        for (int j = 0; j < KBM; j++) a[j] = 0.f;
        const float* ep2 = enc + ((size_t)b * TT + t) * HD + kb;
#pragma unroll 4
        for (int k = 0; k < 256; k += 4) {
          v4f e = *(const v4f*)(ep2 + k);
#pragma unroll
          for (int j = 0; j < KBM; j++) {
            v4f hj = *(const v4f*)&sh_h5[j][kb + k];
            a[j] += hj[0] * e[0] + hj[1] * e[1] + hj[2] * e[2] + hj[3] * e[3];
          }
        }
#pragma unroll
        for (int j = 0; j < KBM; j++) sh_part[half][j][t] = a[j];
      }
      __syncthreads();
      if (tid < 256) {
#pragma unroll
        for (int j = 0; j < KBM; j++) {
          float sc = (sh_part[0][j][tid] + sh_part[1][j][tid]) * SCALEF;
          sh_sc5[j][tid] = sc;
          sh_tmp5[j][tid] = sc;
        }
      }
      __syncthreads();
      for (int off = 128; off > 0; off >>= 1) {
        if (tid < off) {
#pragma unroll
          for (int j = 0; j < KBM; j++)
            sh_tmp5[j][tid] = fmaxf(sh_tmp5[j][tid], sh_tmp5[j][tid + off]);
        }
        __syncthreads();
      }
      float mj[KBM];
#pragma unroll
      for (int j = 0; j < KBM; j++) mj[j] = sh_tmp5[j][0];
      __syncthreads();
      if (tid < 256) {
#pragma unroll
        for (int j = 0; j < KBM; j++) {
          float e = expf(sh_sc5[j][tid] - mj[j]);
          sh_sc5[j][tid] = e;
          sh_tmp5[j][tid] = e;
        }
      }
      __syncthreads();
      for (int off = 128; off > 0; off >>= 1) {
        if (tid < off) {
#pragma unroll
          for (int j = 0; j < KBM; j++) sh_tmp5[j][tid] += sh_tmp5[j][tid + off];
        }
        __syncthreads();
      }
      float Sj[KBM];
#pragma unroll
      for (int j = 0; j < KBM; j++) Sj[j] = sh_tmp5[j][0];
      __syncthreads();
      if (tid < 256) {
#pragma unroll
        for (int j = 0; j < KBM; j++) sh_sc5[j][tid] = sh_sc5[j][tid] / Sj[j];
      }
      __syncthreads();
      {  // context: thread = column
        float cx[KBM];
#pragma unroll
        for (int j = 0; j < KBM; j++) cx[j] = 0.f;
        const float* eb = enc + (size_t)b * TT * HD + tid;
#pragma unroll 4
        for (int t2 = 0; t2 < TT; t2++) {
          float e = eb[(size_t)t2 * HD];
#pragma unroll
          for (int j = 0; j < KBM; j++) cx[j] += sh_sc5[j][t2] * e;
        }
#pragma unroll
        for (int j = 0; j < KBM; j++)
          st_sysf(&A_cat[(size_t)(b * KBM + j) * 1024 + HD + tid], cx[j]);
      }
    }
    gbar();

    // ============ output GEMM + fused row summaries (200 blocks) ==========
    if (bid < 200) {
      const int bc = bid % 40, br = bid / 40;
      const int c0 = bc * 128, n0 = br * 32;
      const int tx = tid & 31, ty = tid >> 5;     // ty 0..15, 2 rows each
      float acc[2][4];
#pragma unroll
      for (int rr = 0; rr < 2; rr++)
#pragma unroll
        for (int cc = 0; cc < 4; cc++) acc[rr][cc] = 0.f;

      for (int k0 = 0; k0 < 1024; k0 += 64) {
        __syncthreads();
#pragma unroll
        for (int p = 0; p < 4; p++) {
          int idx = tid + p * NTHR;
          int kk = idx >> 5, c4 = (idx & 31) * 4;
          int col = c0 + c4;
          v4f v;
          if (col + 3 < VV) v = *(const v4f*)&w_out[(size_t)(k0 + kk) * VV + col];
          else { v[0] = v[1] = v[2] = v[3] = 0.f; }
          *(v4f*)&sh_bs[kk][c4] = v;
        }
        {
          int r = tid >> 4, k4 = (tid & 15) * 4;
          *(v4f*)&sh_as[r][k4] = ld4_sys(&A_cat[(size_t)(n0 + r) * 1024 + k0 + k4]);
        }
        __syncthreads();
#pragma unroll 16
        for (int k = 0; k < 64; k++) {
          v4f bv = *(const v4f*)&sh_bs[k][tx * 4];
#pragma unroll
          for (int rr = 0; rr < 2; rr++) {
            float a = sh_as[ty * 2 + rr][k];
            acc[rr][0] += a * bv[0]; acc[rr][1] += a * bv[1];
            acc[rr][2] += a * bv[2]; acc[rr][3] += a * bv[3];
          }
        }
      }
      // ---- fused epilogue: per-row (m, sumexp, top5) over this tile ----
#pragma unroll
      for (int rr = 0; rr < 2; rr++) {
        const int rowg = n0 + ty * 2 + rr;
        float vv[4]; int ci[4];
        float m = NEGBIG, s = 0.f;
#pragma unroll
        for (int cc = 0; cc < 4; cc++) {
          int c = c0 + tx * 4 + cc;
          ci[cc] = c;
          if (c < VV) {
            float x = acc[rr][cc];
            vv[cc] = x;
            float mn = fmaxf(m, x);
            s = s * expf(m - mn) + expf(x - mn);
            m = mn;
          } else {
            vv[cc] = NEGBIG;
          }
        }
        // half-wave (32-lane) lse combine
#pragma unroll
        for (int d = 1; d < 32; d <<= 1) {
          float om = __shfl_xor(m, d), os = __shfl_xor(s, d);
          float mm = fmaxf(m, om);
          s = s * expf(m - mm) + os * expf(om - mm);
          m = mm;
        }
        // 5x extract-max over the 128 cols (32 lanes x 4 each)
        float tv[5]; int ti[5];
#pragma unroll
        for (int q = 0; q < 5; q++) {
          float bvv = vv[0]; int bii = ci[0];
#pragma unroll
          for (int cc = 1; cc < 4; cc++)
            if (viBetter(vv[cc], ci[cc], bvv, bii)) { bvv = vv[cc]; bii = ci[cc]; }
          bfly_argmax<5>(bvv, bii);
          tv[q] = bvv; ti[q] = bii;
#pragma unroll
          for (int cc = 0; cc < 4; cc++)
            if (ci[cc] == bii) vv[cc] = -3.2e38f;
        }
        if ((tid & 31) == 0) {
          int base = rowg * 40 + bc;
          st_sysf(&sumM[base], m);
          st_sysf(&sumS[base], s);
#pragma unroll
          for (int q = 0; q < 5; q++) {
            st_sysf(&sumV[base * 5 + q], tv[q]);
            st_sysi(&sumI[base * 5 + q], ti[q]);
          }
        }
      }
    }
    gbar();

    // ============ top-k + state update (32 blocks: per batch) =============
    if (bid < BB) {
      const int b = bid;
      if (tid < KBM) {
        sh_oc[tid] = sh_cum[tid]; sh_ofin[tid] = sh_fin[tid]; sh_olen[tid] = sh_len[tid];
      }
      for (int t = tid; t < KBM * MAXLEN; t += NTHR) sh_ttmp[t] = sh_tokens[t >> 6][t & 63];
      __syncthreads();

      const int w = tid >> 6, lane = tid & 63;
      const bool act = (di == 0) ? (w == 0) : (w < KBM);
      if (act) {
        const int j = (di == 0) ? 0 : w;
        if (di > 0 && sh_ofin[j]) {
          if (lane == 0) {
            float cj = sh_oc[j];
            sh_candV[j * KBM + 0] = cj;              // PAD at zero log-prob
            sh_candI[j * KBM + 0] = j * VV + 0;
#pragma unroll
            for (int q = 1; q < KBM; q++) {
              sh_candV[j * KBM + q] = cj + NEGV;
              sh_candI[j * KBM + q] = j * VV + q;
            }
          }
        } else {
          const int row = b * KBM + j;
          float m, s; float lv[5]; int li[5];
          if (lane < 40) {
            int base = row * 40 + lane;
            m = ld_sysf(&sumM[base]); s = ld_sysf(&sumS[base]);
#pragma unroll
            for (int q = 0; q < 5; q++) {
              lv[q] = ld_sysf(&sumV[base * 5 + q]);
              li[q] = ld_sysi(&sumI[base * 5 + q]);
            }
          } else {
            m = NEGBIG; s = 0.f;
#pragma unroll
            for (int q = 0; q < 5; q++) { lv[q] = NEGBIG; li[q] = 0x7fffffff; }
          }
#pragma unroll
          for (int d = 1; d < 64; d <<= 1) {
            float om = __shfl_xor(m, d), os = __shfl_xor(s, d);
            float mm = fmaxf(m, om);
            s = s * expf(m - mm) + os * expf(om - mm);
            m = mm;
          }
          float lse = m + logf(s);
          float cj = (di == 0) ? 0.f : sh_oc[j];
#pragma unroll
          for (int q = 0; q < 5; q++) {
            float bvv = lv[0]; int bii = li[0];
#pragma unroll
            for (int p = 1; p < 5; p++)
              if (viBetter(lv[p], li[p], bvv, bii)) { bvv = lv[p]; bii = li[p]; }
            bfly_argmax<6>(bvv, bii);
            if (lane == 0) {
              sh_candV[j * KBM + q] = cj + (bvv - lse);
              sh_candI[j * KBM + q] = j * VV + bii;
            }
#pragma unroll
            for (int p = 0; p < 5; p++)
              if (li[p] == bii) lv[p] = -3.2e38f;
          }
        }
      }
      __syncthreads();
      if (tid == 0) {
        if (di == 0) {
#pragma unroll
          for (int q = 0; q < KBM; q++) { sh_selV[q] = sh_candV[q]; sh_selI[q] = sh_candI[q]; }
        } else {
          float fv[5]; int fi[5];
#pragma unroll
          for (int q = 0; q < 5; q++) { fv[q] = -INFINITY; fi[q] = 0x7fffffff; }
          for (int t = 0; t < KBM * KBM; t++)
            top5_insert(fv, fi, sh_candV[t], sh_candI[t]);
#pragma unroll
          for (int q = 0; q < 5; q++) { sh_selV[q] = fv[q]; sh_selI[q] = fi[q]; }
        }
      }
      __syncthreads();
      if (tid < KBM) {
        int p = tid, idx = sh_selI[p];
        int bm = idx / VV, tk = idx - bm * VV;
        int pf = sh_ofin[bm];
        sh_cum[p] = sh_selV[p];
        sh_len[p] = sh_olen[bm] + (pf ? 0 : 1);
        sh_fin[p] = (pf || tk == EOSID) ? 1 : 0;
        st_sysi(&last_tok[b * KBM + p], tk);
      }
      for (int t = tid; t < KBM * MAXLEN; t += NTHR) {
        int p = t >> 6, pos = t & 63;
        int idx = sh_selI[p]; int bm = idx / VV; int tk = idx - bm * VV;
        sh_tokens[p][pos] = (pos == di) ? tk : sh_ttmp[bm * MAXLEN + pos];
      }
      for (int idx = tid; idx < 640; idx += NTHR) {
        int p = idx >> 7, e4 = (idx & 127) * 4;
        int bm = sh_selI[p] / VV;
        v4f v = ld4_sys(&A_cat[(size_t)(b * KBM + bm) * 1024 + e4]);
        st4_sys(&h[(size_t)(b * KBM + p) * HD + e4], v);
      }
    }
    gbar();
  }

  // ================= final: length penalty, best beam, outputs ============
  if (bid < BB) {
    const int b = bid;
    if (tid == 0) {
      int best = 0; float bv = -INFINITY;
#pragma unroll
      for (int jj = 0; jj < KBM; jj++) {
        float c = sh_cum[jj];
        float pen = powf((5.0f + (float)sh_len[jj]) / 6.0f, 1.2f);
        float sel = sh_fin[jj] ? (c / pen) : c;
        if (sel > bv) { bv = sel; best = jj; }
      }
      sh_selI[0] = best;
    }
    __syncthreads();
    if (tid < MAXLEN) out[b * MAXLEN + tid] = (float)sh_tokens[sh_selI[0]][tid];
    if (tid < KBM) out[BB * MAXLEN + b * KBM + tid] = sh_cum[tid];
  }
}

extern "C" void kernel_launch(void* const* d_in, const int* in_sizes, int n_in,
                              void* d_out, int out_size, void* d_ws, size_t ws_size,
                              hipStream_t stream) {
  (void)in_sizes; (void)n_in; (void)out_size; (void)ws_size;
  const int*   input_var = (const int*)d_in[0];
  const float* enc       = (const float*)d_in[1];
  const float* emb       = (const float*)d_in[2];
  const float* w_ih      = (const float*)d_in[3];
  const float* w_hh      = (const float*)d_in[4];
  const float* w_out     = (const float*)d_in[5];
  float* out = (float*)d_out;

  float* h       = (float*)d_ws;                       // 160*512
  float* A_cat   = h + (size_t)NR * HD;                // 160*1024
  float* sumM    = A_cat + (size_t)NR * 1024;          // 160*40
  float* sumS    = sumM + NR * 40;                     // 160*40
  float* sumV    = sumS + NR * 40;                     // 160*40*5
  int*   sumI    = (int*)(sumV + NR * 40 * 5);         // 160*40*5
  int*   last_tok = sumI + NR * 40 * 5;                // 160
  unsigned int* bar = (unsigned int*)(last_tok + NR);  // 320 uints

  k_zero<<<1, 512, 0, stream>>>(bar);
  k_persist<<<NBLK, NTHR, 0, stream>>>(input_var, enc, emb, w_ih, w_hh, w_out, out,
                                       h, A_cat, sumM, sumS, sumV, sumI,
                                       last_tok, bar);
}

// Round 6
// 9458.321 us; speedup vs baseline: 2.3948x; 1.0440x over previous
//
#include <hip/hip_runtime.h>
#include <math.h>

// Problem constants
#define BB     32      // batch
#define KBM    5       // beam width
#define NR     160     // BB*KBM rows (beam-major)
#define HD     512     // hidden
#define TT     256     // encoder time steps
#define VV     5000    // vocab
#define MAXLEN 64
#define EOSID  2
#define NEGV   (-1e9f)
#define NEGBIG (-3.0e38f)
#define SCALEF 0.04419417382415922f  // 1/sqrt(512)
#define NBLK   256
#define NTHR   512

typedef float v4f __attribute__((ext_vector_type(4)));

// ---- coherent (L2-bypass) scalar ops for small mutable data ----
__device__ __forceinline__ float ld_sysf(const float* p) {
  return __hip_atomic_load(p, __ATOMIC_RELAXED, __HIP_MEMORY_SCOPE_SYSTEM);
}
__device__ __forceinline__ void st_sysf(float* p, float v) {
  __hip_atomic_store(p, v, __ATOMIC_RELAXED, __HIP_MEMORY_SCOPE_SYSTEM);
}
__device__ __forceinline__ int ld_sysi(const int* p) {
  return __hip_atomic_load(p, __ATOMIC_RELAXED, __HIP_MEMORY_SCOPE_SYSTEM);
}
__device__ __forceinline__ void st_sysi(int* p, int v) {
  __hip_atomic_store(p, v, __ATOMIC_RELAXED, __HIP_MEMORY_SCOPE_SYSTEM);
}

// ---- non-blocking issue + register-bound wait (issue-early / bind-late) ----
__device__ __forceinline__ v4f ld4_issue_sys(const float* p) {   // bypass, coherent
  v4f v;
  asm volatile("global_load_dwordx4 %0, %1, off sc0 sc1" : "=v"(v) : "v"(p));
  return v;
}
__device__ __forceinline__ v4f ld4_issue(const float* p) {       // cached
  v4f v;
  asm volatile("global_load_dwordx4 %0, %1, off" : "=v"(v) : "v"(p));
  return v;
}
__device__ __forceinline__ void vm_bind2(v4f& a, v4f& b) {
  asm volatile("s_waitcnt vmcnt(0)" : "+v"(a), "+v"(b) :: "memory");
}
__device__ __forceinline__ void vm_bind3(v4f& a, v4f& b, v4f& c) {
  asm volatile("s_waitcnt vmcnt(0)" : "+v"(a), "+v"(b), "+v"(c) :: "memory");
}
__device__ __forceinline__ void vm_bind4(v4f& a, v4f& b, v4f& c, v4f& d) {
  asm volatile("s_waitcnt vmcnt(0)" : "+v"(a), "+v"(b), "+v"(c), "+v"(d) :: "memory");
}
__device__ __forceinline__ void vm_bind5(v4f& a, v4f& b, v4f& c, v4f& d, v4f& e) {
  asm volatile("s_waitcnt vmcnt(0)"
               : "+v"(a), "+v"(b), "+v"(c), "+v"(d), "+v"(e) :: "memory");
}
__device__ __forceinline__ void st4_sys(float* p, v4f v) {
  asm volatile("global_store_dwordx4 %0, %1, off sc0 sc1" :: "v"(p), "v"(v) : "memory");
}

// comparator matching jax.lax.top_k stability: value desc, index asc on ties
__device__ __forceinline__ bool viBetter(float av, int ai, float bv, int bi) {
  return (av > bv) || (av == bv && ai < bi);
}

__device__ __forceinline__ void top5_insert(float tv[5], int ti[5], float x, int v) {
  if (!viBetter(x, v, tv[4], ti[4])) return;
  tv[4] = x; ti[4] = v;
#pragma unroll
  for (int q = 4; q > 0; q--) {
    if (viBetter(tv[q], ti[q], tv[q - 1], ti[q - 1])) {
      float tf = tv[q - 1]; int tx2 = ti[q - 1];
      tv[q - 1] = tv[q]; ti[q - 1] = ti[q];
      tv[q] = tf; ti[q] = tx2;
    } else break;
  }
}

template<int LEVELS>
__device__ __forceinline__ void bfly_argmax(float& v, int& i) {
#pragma unroll
  for (int d = 1; d < (1 << LEVELS); d <<= 1) {
    float ov = __shfl_xor(v, d);
    int oi = __shfl_xor(i, d);
    if (viBetter(ov, oi, v, i)) { v = ov; i = oi; }
  }
}

__global__ void k_zero(unsigned int* bar) {
  if (threadIdx.x < 320)
    __hip_atomic_store(&bar[threadIdx.x], 0u, __ATOMIC_RELAXED, __HIP_MEMORY_SCOPE_SYSTEM);
}

__launch_bounds__(NTHR, 1)
__global__ void k_persist(const int* __restrict__ input_var, const float* __restrict__ enc,
                          const float* __restrict__ emb, const float* __restrict__ w_ih,
                          const float* __restrict__ w_hh, const float* __restrict__ w_out,
                          float* __restrict__ out,
                          float* h, float* A_cat, float* summ,
                          int* last_tok, unsigned int* bar) {
  const int bid = blockIdx.x;
  const int tid = threadIdx.x;
  unsigned int ep = 0;

  // ---------------- shared memory (~113KB -> 1 block/CU) ----------------
  __shared__ float sh_xs[32][40];
  __shared__ float sh_hs[32][40];
  __shared__ float sh_ws[6][32][32];
  __shared__ int   sh_toks[32];
  __shared__ float sh_h5[KBM][HD];
  __shared__ float sh_part[2][KBM][TT];
  __shared__ float sh_sc5[KBM][TT];
  __shared__ float sh_tmp5[KBM][TT];
  __shared__ float sh_as[32][72];
  __shared__ float sh_bs[64][136];
  __shared__ float sh_candV[KBM * KBM]; __shared__ int sh_candI[KBM * KBM];
  __shared__ int   sh_tokens[KBM][MAXLEN];   // persistent per-batch state (bid<32)
  __shared__ float sh_cum[KBM];
  __shared__ int   sh_fin[KBM]; __shared__ int sh_len[KBM];
  __shared__ float sh_oc[KBM];  __shared__ int sh_ofin[KBM]; __shared__ int sh_olen[KBM];
  __shared__ int   sh_ttmp[KBM * MAXLEN];
  __shared__ int   sh_selI[KBM]; __shared__ float sh_selV[KBM];

  // ---- fence-free tree barrier: 8 spread counters + epoch flag ----
  auto gbar = [&]() {
    asm volatile("s_waitcnt vmcnt(0)" ::: "memory");   // drain outstanding stores
    __syncthreads();
    ep += 1;
    if (tid == 0) {
      __hip_atomic_fetch_add(&bar[(bid & 7) * 32], 1u, __ATOMIC_RELAXED,
                             __HIP_MEMORY_SCOPE_SYSTEM);
      if (bid == 0) {
        for (int c = 0; c < 8; c++) {
          while (__hip_atomic_load(&bar[c * 32], __ATOMIC_RELAXED,
                                   __HIP_MEMORY_SCOPE_SYSTEM) < ep * 32u) {
            __builtin_amdgcn_s_sleep(1);
          }
        }
        __hip_atomic_store(&bar[288], ep, __ATOMIC_RELAXED, __HIP_MEMORY_SCOPE_SYSTEM);
      } else {
        while (__hip_atomic_load(&bar[288], __ATOMIC_RELAXED,
                                 __HIP_MEMORY_SCOPE_SYSTEM) < ep) {
          __builtin_amdgcn_s_sleep(2);
        }
      }
    }
    __syncthreads();
  };

  // ---------------- init ----------------
  if (bid < BB) {
    if (tid < KBM) { sh_cum[tid] = 0.f; sh_fin[tid] = 0; sh_len[tid] = 0; }
    for (int t = tid; t < KBM * MAXLEN; t += NTHR) sh_tokens[t >> 6][t & 63] = 0;
  }
  {
    int gidx = bid * NTHR + tid;
    v4f z4; z4[0] = z4[1] = z4[2] = z4[3] = 0.f;
    for (int i = gidx; i < NR * HD / 4; i += NBLK * NTHR) st4_sys(&h[i * 4], z4);
    for (int t = gidx; t < NR; t += NBLK * NTHR) st_sysi(&last_tok[t], input_var[t / KBM]);
  }
  gbar();

  for (int di = 0; di < MAXLEN; di++) {
    // ============ GRU (80 blocks: 16 col-tiles x 5 row-tiles, 32x32) ======
    if (bid < 80) {
      const int bx = bid & 15, by = bid >> 4;
      const int i0 = bx * 32, n0 = by * 32;
      const int tx = tid & 31, ty = tid >> 5;    // ty 0..15, 2 rows each
      if (tid < 32) sh_toks[tid] = ld_sysi(&last_tok[n0 + tid]);
      float acc[6][2];
#pragma unroll
      for (int g = 0; g < 6; g++) { acc[g][0] = 0.f; acc[g][1] = 0.f; }
      float hcap0 = 0.f, hcap1 = 0.f;

      for (int k0 = 0; k0 < HD; k0 += 32) {
        __syncthreads();
        // ---- issue all staging loads, bind once, then LDS-write ----
        v4f v0, v1, v2, v3;
        if (tid < 256) {
          int r = tid >> 3, c4 = (tid & 7) * 4;
          v0 = ld4_issue(&emb[(size_t)sh_toks[r] * HD + k0 + c4]);
        } else {
          int r = (tid - 256) >> 3, c4 = ((tid - 256) & 7) * 4;
          v0 = ld4_issue_sys(&h[(size_t)(n0 + r) * HD + k0 + c4]);
        }
        int gW[3], kW[3], cW[3];
#pragma unroll
        for (int p = 0; p < 3; p++) {
          int widx = tid + p * 512;
          int g = widx >> 8, rem = widx & 255;
          int kk = rem >> 3, c4 = (rem & 7) * 4;
          const float* W = (g < 3) ? w_ih : w_hh;
          int gc = (g < 3) ? g : g - 3;
          v4f t = ld4_issue(&W[(size_t)(k0 + kk) * 1536 + gc * HD + i0 + c4]);
          if (p == 0) v1 = t; else if (p == 1) v2 = t; else v3 = t;
          gW[p] = g; kW[p] = kk; cW[p] = c4;
        }
        vm_bind4(v0, v1, v2, v3);
        if (tid < 256) {
          int r = tid >> 3, c4 = (tid & 7) * 4;
          *(v4f*)&sh_xs[r][c4] = v0;
        } else {
          int r = (tid - 256) >> 3, c4 = ((tid - 256) & 7) * 4;
          *(v4f*)&sh_hs[r][c4] = v0;
        }
        *(v4f*)&sh_ws[gW[0]][kW[0]][cW[0]] = v1;
        *(v4f*)&sh_ws[gW[1]][kW[1]][cW[1]] = v2;
        *(v4f*)&sh_ws[gW[2]][kW[2]][cW[2]] = v3;
        __syncthreads();
        if (k0 == i0) {                     // capture gate h-input from LDS
          hcap0 = sh_hs[ty * 2 + 0][tx];
          hcap1 = sh_hs[ty * 2 + 1][tx];
        }
#pragma unroll 8
        for (int k = 0; k < 32; k++) {
          float w0 = sh_ws[0][k][tx], w1 = sh_ws[1][k][tx], w2 = sh_ws[2][k][tx];
          float w3 = sh_ws[3][k][tx], w4 = sh_ws[4][k][tx], w5 = sh_ws[5][k][tx];
#pragma unroll
          for (int rr = 0; rr < 2; rr++) {
            float xv = sh_xs[ty * 2 + rr][k];
            float hv = sh_hs[ty * 2 + rr][k];
            acc[0][rr] += xv * w0; acc[1][rr] += xv * w1; acc[2][rr] += xv * w2;
            acc[3][rr] += hv * w3; acc[4][rr] += hv * w4; acc[5][rr] += hv * w5;
          }
        }
      }
#pragma unroll
      for (int rr = 0; rr < 2; rr++) {
        int n = n0 + ty * 2 + rr, i = i0 + tx;
        float hv = rr ? hcap1 : hcap0;
        float z = 1.f / (1.f + expf(-(acc[0][rr] + acc[3][rr])));
        float r = 1.f / (1.f + expf(-(acc[1][rr] + acc[4][rr])));
        float nn = tanhf(acc[2][rr] + r * acc[5][rr]);
        st_sysf(&A_cat[(size_t)n * 1024 + i], (1.f - z) * nn + z * hv);
      }
    }
    gbar();

    // ============ attention (32 blocks: one per batch) ====================
    if (bid < BB) {
      const int b = bid;
      {
        v4f x0, x1 = {};
        int j0 = tid >> 7, kc0 = (tid & 127) * 4;
        x0 = ld4_issue_sys(&A_cat[(size_t)(b * KBM + j0) * 1024 + kc0]);
        if (tid < 128) {
          int idx = tid + 512;
          x1 = ld4_issue_sys(&A_cat[(size_t)(b * KBM + (idx >> 7)) * 1024 + (idx & 127) * 4]);
        }
        vm_bind2(x0, x1);
        *(v4f*)&sh_h5[j0][kc0] = x0;
        if (tid < 128) {
          int idx = tid + 512;
          *(v4f*)&sh_h5[idx >> 7][(idx & 127) * 4] = x1;
        }
      }
      __syncthreads();
      {
        const int t = tid & 255, half = tid >> 8;
        const int kb = half * 256;
        float a[KBM];
#pragma unroll
        for (int j = 0; j < KBM; j++) a[j] = 0.f;
        const float* ep2 = enc + ((size_t)b * TT + t) * HD + kb;
#pragma unroll 4
        for (int k = 0; k < 256; k += 4) {
          v4f e = *(const v4f*)(ep2 + k);
#pragma unroll
          for (int j = 0; j < KBM; j++) {
            v4f hj = *(const v4f*)&sh_h5[j][kb + k];
            a[j] += hj[0] * e[0] + hj[1] * e[1] + hj[2] * e[2] + hj[3] * e[3];
          }
        }
#pragma unroll
        for (int j = 0; j < KBM; j++) sh_part[half][j][t] = a[j];
      }
      __syncthreads();
      if (tid < 256) {
#pragma unroll
        for (int j = 0; j < KBM; j++) {
          float sc = (sh_part[0][j][tid] + sh_part[1][j][tid]) * SCALEF;
          sh_sc5[j][tid] = sc;
          sh_tmp5[j][tid] = sc;
        }
      }
      __syncthreads();
      for (int off = 128; off > 0; off >>= 1) {
        if (tid < off) {
#pragma unroll
          for (int j = 0; j < KBM; j++)
            sh_tmp5[j][tid] = fmaxf(sh_tmp5[j][tid], sh_tmp5[j][tid + off]);
        }
        __syncthreads();
      }
      float mj[KBM];
#pragma unroll
      for (int j = 0; j < KBM; j++) mj[j] = sh_tmp5[j][0];
      __syncthreads();
      if (tid < 256) {
#pragma unroll
        for (int j = 0; j < KBM; j++) {
          float e = expf(sh_sc5[j][tid] - mj[j]);
          sh_sc5[j][tid] = e;
          sh_tmp5[j][tid] = e;
        }
      }
      __syncthreads();
      for (int off = 128; off > 0; off >>= 1) {
        if (tid < off) {
#pragma unroll
          for (int j = 0; j < KBM; j++) sh_tmp5[j][tid] += sh_tmp5[j][tid + off];
        }
        __syncthreads();
      }
      float Sj[KBM];
#pragma unroll
      for (int j = 0; j < KBM; j++) Sj[j] = sh_tmp5[j][0];
      __syncthreads();
      if (tid < 256) {
#pragma unroll
        for (int j = 0; j < KBM; j++) sh_sc5[j][tid] = sh_sc5[j][tid] / Sj[j];
      }
      __syncthreads();
      {  // context: thread = column (coalesced enc reads, L2-hot)
        float cx[KBM];
#pragma unroll
        for (int j = 0; j < KBM; j++) cx[j] = 0.f;
        const float* eb = enc + (size_t)b * TT * HD + tid;
#pragma unroll 8
        for (int t2 = 0; t2 < TT; t2++) {
          float e = eb[(size_t)t2 * HD];
#pragma unroll
          for (int j = 0; j < KBM; j++) cx[j] += sh_sc5[j][t2] * e;
        }
#pragma unroll
        for (int j = 0; j < KBM; j++)
          st_sysf(&A_cat[(size_t)(b * KBM + j) * 1024 + HD + tid], cx[j]);
      }
    }
    gbar();

    // ============ output GEMM + fused row summaries (200 blocks) ==========
    if (bid < 200) {
      const int bc = bid % 40, br = bid / 40;
      const int c0 = bc * 128, n0 = br * 32;
      const int tx = tid & 31, ty = tid >> 5;     // ty 0..15, 2 rows each
      float acc[2][4];
#pragma unroll
      for (int rr = 0; rr < 2; rr++)
#pragma unroll
        for (int cc = 0; cc < 4; cc++) acc[rr][cc] = 0.f;

      for (int k0 = 0; k0 < 1024; k0 += 64) {
        __syncthreads();
        // ---- issue A (bypass) + 4x B (cached), bind once, LDS-write ----
        v4f a0, b0, b1, b2, b3;
        const int ar = tid >> 4, ak4 = (tid & 15) * 4;
        a0 = ld4_issue_sys(&A_cat[(size_t)(n0 + ar) * 1024 + k0 + ak4]);
        int kkB[4], cB[4];
#pragma unroll
        for (int p = 0; p < 4; p++) {
          int idx = tid + p * 512;
          int kk = idx >> 5, c4 = (idx & 31) * 4;
          int col = c0 + c4;
          v4f t; t[0] = t[1] = t[2] = t[3] = 0.f;
          if (col + 3 < VV) t = ld4_issue(&w_out[(size_t)(k0 + kk) * VV + col]);
          if (p == 0) b0 = t; else if (p == 1) b1 = t; else if (p == 2) b2 = t; else b3 = t;
          kkB[p] = kk; cB[p] = c4;
        }
        vm_bind5(a0, b0, b1, b2, b3);
        *(v4f*)&sh_as[ar][ak4] = a0;
        *(v4f*)&sh_bs[kkB[0]][cB[0]] = b0;
        *(v4f*)&sh_bs[kkB[1]][cB[1]] = b1;
        *(v4f*)&sh_bs[kkB[2]][cB[2]] = b2;
        *(v4f*)&sh_bs[kkB[3]][cB[3]] = b3;
        __syncthreads();
#pragma unroll 16
        for (int k = 0; k < 64; k++) {
          v4f bv = *(const v4f*)&sh_bs[k][tx * 4];
#pragma unroll
          for (int rr = 0; rr < 2; rr++) {
            float a = sh_as[ty * 2 + rr][k];
            acc[rr][0] += a * bv[0]; acc[rr][1] += a * bv[1];
            acc[rr][2] += a * bv[2]; acc[rr][3] += a * bv[3];
          }
        }
      }
      // ---- fused epilogue: per-row (m, sumexp, top5) over this tile ----
#pragma unroll
      for (int rr = 0; rr < 2; rr++) {
        const int rowg = n0 + ty * 2 + rr;
        float vv[4]; int ci[4];
        float m = NEGBIG, s = 0.f;
#pragma unroll
        for (int cc = 0; cc < 4; cc++) {
          int c = c0 + tx * 4 + cc;
          ci[cc] = c;
          if (c < VV) {
            float x = acc[rr][cc];
            vv[cc] = x;
            float mn = fmaxf(m, x);
            s = s * expf(m - mn) + expf(x - mn);
            m = mn;
          } else {
            vv[cc] = NEGBIG;
          }
        }
        // half-wave (32-lane) lse combine
#pragma unroll
        for (int d = 1; d < 32; d <<= 1) {
          float om = __shfl_xor(m, d), os = __shfl_xor(s, d);
          float mm = fmaxf(m, om);
          s = s * expf(m - mm) + os * expf(om - mm);
          m = mm;
        }
        // 5x extract-max over the 128 cols (32 lanes x 4 each)
        float tv[5]; int ti[5];
#pragma unroll
        for (int q = 0; q < 5; q++) {
          float bvv = vv[0]; int bii = ci[0];
#pragma unroll
          for (int cc = 1; cc < 4; cc++)
            if (viBetter(vv[cc], ci[cc], bvv, bii)) { bvv = vv[cc]; bii = ci[cc]; }
          bfly_argmax<5>(bvv, bii);
          tv[q] = bvv; ti[q] = bii;
#pragma unroll
          for (int cc = 0; cc < 4; cc++)
            if (ci[cc] == bii) vv[cc] = -3.2e38f;
        }
        if ((tid & 31) == 0) {
          float* base = &summ[((size_t)rowg * 40 + bc) * 12];
          v4f p0v, p1v, p2v;
          p0v[0] = m; p0v[1] = s; p0v[2] = tv[0]; p0v[3] = tv[1];
          p1v[0] = tv[2]; p1v[1] = tv[3]; p1v[2] = tv[4];
          p1v[3] = __int_as_float(ti[0]);
          p2v[0] = __int_as_float(ti[1]); p2v[1] = __int_as_float(ti[2]);
          p2v[2] = __int_as_float(ti[3]); p2v[3] = __int_as_float(ti[4]);
          st4_sys(base, p0v); st4_sys(base + 4, p1v); st4_sys(base + 8, p2v);
        }
      }
    }
    gbar();

    // ============ top-k + state update (32 blocks: per batch) =============
    if (bid < BB) {
      const int b = bid;
      if (tid < KBM) {
        sh_oc[tid] = sh_cum[tid]; sh_ofin[tid] = sh_fin[tid]; sh_olen[tid] = sh_len[tid];
      }
      for (int t = tid; t < KBM * MAXLEN; t += NTHR) sh_ttmp[t] = sh_tokens[t >> 6][t & 63];
      __syncthreads();

      const int w = tid >> 6, lane = tid & 63;
      const bool act = (di == 0) ? (w == 0) : (w < KBM);
      if (act) {
        const int j = (di == 0) ? 0 : w;
        if (di > 0 && sh_ofin[j]) {
          if (lane == 0) {
            float cj = sh_oc[j];
            sh_candV[j * KBM + 0] = cj;              // PAD at zero log-prob
            sh_candI[j * KBM + 0] = j * VV + 0;
#pragma unroll
            for (int q = 1; q < KBM; q++) {
              sh_candV[j * KBM + q] = cj + NEGV;
              sh_candI[j * KBM + q] = j * VV + q;
            }
          }
        } else {
          const int row = b * KBM + j;
          float m, s; float lv[5]; int li[5];
          if (lane < 40) {
            const float* base = &summ[((size_t)row * 40 + lane) * 12];
            v4f s0 = ld4_issue_sys(base);
            v4f s1 = ld4_issue_sys(base + 4);
            v4f s2 = ld4_issue_sys(base + 8);
            vm_bind3(s0, s1, s2);
            m = s0[0]; s = s0[1];
            lv[0] = s0[2]; lv[1] = s0[3]; lv[2] = s1[0]; lv[3] = s1[1]; lv[4] = s1[2];
            li[0] = __float_as_int(s1[3]);
            li[1] = __float_as_int(s2[0]); li[2] = __float_as_int(s2[1]);
            li[3] = __float_as_int(s2[2]); li[4] = __float_as_int(s2[3]);
          } else {
            m = NEGBIG; s = 0.f;
#pragma unroll
            for (int q = 0; q < 5; q++) { lv[q] = NEGBIG; li[q] = 0x7fffffff; }
          }
#pragma unroll
          for (int d = 1; d < 64; d <<= 1) {
            float om = __shfl_xor(m, d), os = __shfl_xor(s, d);
            float mm = fmaxf(m, om);
            s = s * expf(m - mm) + os * expf(om - mm);
            m = mm;
          }
          float lse = m + logf(s);
          float cj = (di == 0) ? 0.f : sh_oc[j];
#pragma unroll
          for (int q = 0; q < 5; q++) {
            float bvv = lv[0]; int bii = li[0];
#pragma unroll
            for (int p = 1; p < 5; p++)
              if (viBetter(lv[p], li[p], bvv, bii)) { bvv = lv[p]; bii = li[p]; }
            bfly_argmax<6>(bvv, bii);
            if (lane == 0) {
              sh_candV[j * KBM + q] = cj + (bvv - lse);
              sh_candI[j * KBM + q] = j * VV + bii;
            }
#pragma unroll
            for (int p = 0; p < 5; p++)
              if (li[p] == bii) lv[p] = -3.2e38f;
          }
        }
      }
      __syncthreads();
      if (tid == 0) {
        if (di == 0) {
#pragma unroll
          for (int q = 0; q < KBM; q++) { sh_selV[q] = sh_candV[q]; sh_selI[q] = sh_candI[q]; }
        } else {
          float fv[5]; int fi[5];
#pragma unroll
          for (int q = 0; q < 5; q++) { fv[q] = -INFINITY; fi[q] = 0x7fffffff; }
          for (int t = 0; t < KBM * KBM; t++)
            top5_insert(fv, fi, sh_candV[t], sh_candI[t]);
#pragma unroll
          for (int q = 0; q < 5; q++) { sh_selV[q] = fv[q]; sh_selI[q] = fi[q]; }
        }
      }
      __syncthreads();
      if (tid < KBM) {
        int p = tid, idx = sh_selI[p];
        int bm = idx / VV, tk = idx - bm * VV;
        int pf = sh_ofin[bm];
        sh_cum[p] = sh_selV[p];
        sh_len[p] = sh_olen[bm] + (pf ? 0 : 1);
        sh_fin[p] = (pf || tk == EOSID) ? 1 : 0;
        st_sysi(&last_tok[b * KBM + p], tk);
      }
      for (int t = tid; t < KBM * MAXLEN; t += NTHR) {
        int p = t >> 6, pos = t & 63;
        int idx = sh_selI[p]; int bm = idx / VV; int tk = idx - bm * VV;
        sh_tokens[p][pos] = (pos == di) ? tk : sh_ttmp[bm * MAXLEN + pos];
      }
      __syncthreads();
      {
        // h <- A_cat[selected beam] (first 512 cols): issue both slots, bind once
        int p0 = tid >> 7, e40 = (tid & 127) * 4;
        int bm0 = sh_selI[p0] / VV;
        v4f y0 = ld4_issue_sys(&A_cat[(size_t)(b * KBM + bm0) * 1024 + e40]);
        v4f y1 = {};
        if (tid < 128) {
          int bm1 = sh_selI[4] / VV;
          y1 = ld4_issue_sys(&A_cat[(size_t)(b * KBM + bm1) * 1024 + tid * 4]);
        }
        vm_bind2(y0, y1);
        st4_sys(&h[(size_t)(b * KBM + p0) * HD + e40], y0);
        if (tid < 128) st4_sys(&h[(size_t)(b * KBM + 4) * HD + tid * 4], y1);
      }
    }
    gbar();
  }

  // ================= final: length penalty, best beam, outputs ============
  if (bid < BB) {
    const int b = bid;
    if (tid == 0) {
      int best = 0; float bv = -INFINITY;
#pragma unroll
      for (int jj = 0; jj < KBM; jj++) {
        float c = sh_cum[jj];
        float pen = powf((5.0f + (float)sh_len[jj]) / 6.0f, 1.2f);
        float sel = sh_fin[jj] ? (c / pen) : c;
        if (sel > bv) { bv = sel; best = jj; }
      }
      sh_selI[0] = best;
    }
    __syncthreads();
    if (tid < MAXLEN) out[b * MAXLEN + tid] = (float)sh_tokens[sh_selI[0]][tid];
    if (tid < KBM) out[BB * MAXLEN + b * KBM + tid] = sh_cum[tid];
  }
}

extern "C" void kernel_launch(void* const* d_in, const int* in_sizes, int n_in,
                              void* d_out, int out_size, void* d_ws, size_t ws_size,
                              hipStream_t stream) {
  (void)in_sizes; (void)n_in; (void)out_size; (void)ws_size;
  const int*   input_var = (const int*)d_in[0];
  const float* enc       = (const float*)d_in[1];
  const float* emb       = (const float*)d_in[2];
  const float* w_ih      = (const float*)d_in[3];
  const float* w_hh      = (const float*)d_in[4];
  const float* w_out     = (const float*)d_in[5];
  float* out = (float*)d_out;

  float* h       = (float*)d_ws;                       // 160*512
  float* A_cat   = h + (size_t)NR * HD;                // 160*1024
  float* summ    = A_cat + (size_t)NR * 1024;          // 160*40*12
  int*   last_tok = (int*)(summ + (size_t)NR * 40 * 12);  // 160
  unsigned int* bar = (unsigned int*)(last_tok + NR);  // 320 uints

  k_zero<<<1, 512, 0, stream>>>(bar);
  k_persist<<<NBLK, NTHR, 0, stream>>>(input_var, enc, emb, w_ih, w_hh, w_out, out,
                                       h, A_cat, summ, last_tok, bar);
}